// Round 10
// baseline (208.832 us; speedup 1.0000x reference)
//
#include <hip/hip_runtime.h>
#include <hip/hip_bf16.h>

typedef __bf16 bf16;
typedef __bf16 bf16x4 __attribute__((ext_vector_type(4)));
typedef __bf16 bf16x8 __attribute__((ext_vector_type(8)));
typedef float f32x4 __attribute__((ext_vector_type(4)));

#define B_ 2
#define S_ 2048
#define H_ 16
#define DH_ 64
#define D_ 1024
#define NT_ 4096  // B_*S_

// Ordering notes (R2 post-mortem): global_load_lds retires on vmcnt, ds_* on
// lgkmcnt. Two edges MUST be explicit:
//   (1) vmcnt(0) before the barrier that publishes freshly staged LDS tiles.
//   (2) lgkmcnt(0) between a wave's own ds_write and its ds_read of the same
//       bytes (sP round-trip, psum broadcast).
// R6+R8 lesson: explicit double-buffering regressed twice — at 8 waves/CU the
// implicit TLP overlap already hides staging latency.
#define WAIT_VMCNT0() asm volatile("s_waitcnt vmcnt(0)" ::: "memory")
#define WAIT_LGKM0()  asm volatile("s_waitcnt lgkmcnt(0)" ::: "memory")

// async global->LDS, 16B per lane; LDS dest is wave-uniform base + lane*16
__device__ __forceinline__ void gld_lds16(const bf16* g, bf16* l) {
    __builtin_amdgcn_global_load_lds(
        (__attribute__((address_space(1))) void*)g,
        (__attribute__((address_space(3))) void*)l, 16, 0, 0);
}

// fast RNE float->bf16, no NaN/denorm path (inputs are finite, well-scaled)
__device__ __forceinline__ bf16 f2bf(float x) {
    union { float f; unsigned u; } v; v.f = x;
    unsigned short h = (unsigned short)((v.u + 0x7FFF + ((v.u >> 16) & 1)) >> 16);
    return __builtin_bit_cast(bf16, h);
}

// ---------------------------------------------------------------------------
// Kernel 1: fp32 -> bf16 conversion/packing.
// layout: [hs 4194304][Wq|Wk|Wv 3145728][Wo 1048576], 4 elems/thread
// ---------------------------------------------------------------------------
__global__ __launch_bounds__(256) void cvt_kernel(
    const float* __restrict__ hs,
    const float* __restrict__ Wq, const float* __restrict__ Wk,
    const float* __restrict__ Wv, const float* __restrict__ Wo,
    bf16* __restrict__ hsb, bf16* __restrict__ wqkv, bf16* __restrict__ wob)
{
    int i = (blockIdx.x * 256 + threadIdx.x) * 4;
    const float* src;
    bf16* dst;
    if (i < 4194304) {
        src = hs + i; dst = hsb + i;
    } else if (i < 7340032) {
        int off = i - 4194304;
        int which = off >> 20;           // 0=Wq 1=Wk 2=Wv
        int within = off & 1048575;
        src = (which == 0 ? Wq : which == 1 ? Wk : Wv) + within;
        dst = wqkv + off;
    } else {
        int off = i - 7340032;
        src = Wo + off; dst = wob + off;
    }
    float4 v = *(const float4*)src;
    bf16x4 o = { (bf16)v.x, (bf16)v.y, (bf16)v.z, (bf16)v.w };
    *(bf16x4*)dst = o;
}

// ---------------------------------------------------------------------------
// Kernel 2/4: C = A @ B^T (+bias).  A: MxK bf16 row-major, B: NxK bf16 row-major.
// 128x128 tile, BK=32, 4 waves, 4x4 mfma 16x16x32 each.
// R10: __launch_bounds__(256,3) -> 3 blocks/CU so gemm0's 768 blocks run in
// ONE dispatch round (was 2 rounds at 2/CU, second half-empty).
// R10: V is now stored coalesced in (b,h,s,d) like K — the old (b,h,d,s)
// epilogue scatter (2B lanes at 4KB stride) caused ~8x write amplification.
// A separate transpose kernel produces the (b,h,d,s) layout for attn.
// LDS rows (32 elems = 4 groups of 8) XOR-swizzled: conflict-free reads.
// mode 0: QKV epilogue -> Q(xscale)/K/V all to (b,h,s,d) bf16
// mode 1: out epilogue -> fp32 row-major + bias
// ---------------------------------------------------------------------------
__global__ __launch_bounds__(256, 3) void gemm_bt(
    const bf16* __restrict__ A, const bf16* __restrict__ Bm,
    int mode,
    const float* __restrict__ b0, const float* __restrict__ b1,
    const float* __restrict__ b2,
    bf16* __restrict__ Qo, bf16* __restrict__ Ko, bf16* __restrict__ Vo,
    float* __restrict__ Co)
{
    const int K = 1024;
    __shared__ __attribute__((aligned(16))) bf16 sA[128 * 32];
    __shared__ __attribute__((aligned(16))) bf16 sB[128 * 32];

    int tid = threadIdx.x;
    int wave = tid >> 6, lane = tid & 63;
    int quad = lane >> 4, l16 = lane & 15;
    int m0 = blockIdx.x * 128;
    int n0 = blockIdx.y * 128;
    int wm = (wave & 1) * 64, wn = (wave >> 1) * 64;
    int fs = (l16 >> 1) & 3;            // read-side swizzle key

    f32x4 acc[4][4];
#pragma unroll
    for (int i = 0; i < 4; i++)
#pragma unroll
        for (int j = 0; j < 4; j++) acc[i][j] = (f32x4){0.f, 0.f, 0.f, 0.f};

    for (int k0 = 0; k0 < K; k0 += 32) {
#pragma unroll
        for (int i = 0; i < 2; i++) {
            int chunk = tid + i * 256;      // 0..511, 16B each
            int row = chunk >> 2;           // 4 chunks per 32-elem row
            int kc = ((chunk & 3) ^ ((row >> 1) & 3)) * 8;  // swizzled source group
            gld_lds16(A + (size_t)(m0 + row) * K + k0 + kc, &sA[chunk * 8]);
            gld_lds16(Bm + (size_t)(n0 + row) * K + k0 + kc, &sB[chunk * 8]);
        }
        WAIT_VMCNT0();          // async LDS writes landed before barrier
        __syncthreads();

        bf16x8 af[4], bfr[4];
#pragma unroll
        for (int i = 0; i < 4; i++)
            af[i] = *(const bf16x8*)&sA[(wm + i * 16 + l16) * 32 + (quad ^ fs) * 8];
#pragma unroll
        for (int j = 0; j < 4; j++)
            bfr[j] = *(const bf16x8*)&sB[(wn + j * 16 + l16) * 32 + (quad ^ fs) * 8];
#pragma unroll
        for (int i = 0; i < 4; i++)
#pragma unroll
            for (int j = 0; j < 4; j++)
                acc[i][j] = __builtin_amdgcn_mfma_f32_16x16x32_bf16(
                    af[i], bfr[j], acc[i][j], 0, 0, 0);
        __syncthreads();
    }

    // C/D layout: col = lane&15, row = quad*4 + reg  (m89/m91 verified)
    if (mode == 0) {
        const float QSCALE = 0.125f * 1.44269504088896340736f;  // 1/sqrt(64)*log2(e)
#pragma unroll
        for (int j = 0; j < 4; j++) {
            int n = n0 + wn + j * 16 + l16;
            int region = n >> 10;            // block-uniform (n0 128-aligned)
            int nn = n & 1023;
            int h = nn >> 6, d = nn & 63;
            float bias = (region == 0 ? b0 : region == 1 ? b1 : b2)[nn];
#pragma unroll
            for (int i = 0; i < 4; i++)
#pragma unroll
                for (int r = 0; r < 4; r++) {
                    int m = m0 + wm + i * 16 + quad * 4 + r;
                    int b = m >> 11, s = m & 2047;
                    int bh = b * H_ + h;
                    float v = acc[i][j][r] + bias;
                    if (region == 0)
                        Qo[((size_t)bh * S_ + s) * DH_ + d] = f2bf(v * QSCALE);
                    else if (region == 1)
                        Ko[((size_t)bh * S_ + s) * DH_ + d] = f2bf(v);
                    else
                        Vo[((size_t)bh * S_ + s) * DH_ + d] = f2bf(v);  // coalesced now
                }
        }
    } else {
#pragma unroll
        for (int j = 0; j < 4; j++) {
            int n = n0 + wn + j * 16 + l16;
            float bias = b0[n];
#pragma unroll
            for (int i = 0; i < 4; i++)
#pragma unroll
                for (int r = 0; r < 4; r++) {
                    int m = m0 + wm + i * 16 + quad * 4 + r;
                    Co[(size_t)m * D_ + n] = acc[i][j][r] + bias;
                }
        }
    }
}

// ---------------------------------------------------------------------------
// Kernel 2.5 (R10): V (b,h,s,d) -> V^T (b,h,d,s), 64x64 LDS tiles.
// Column-XOR swizzle col' = s ^ 8*(d>>3): scalar tile-writes are 2-way (free),
// b128 tile-reads at the wave64 minimum, both global sides fully coalesced.
// grid (S/64, B*H), ~16 MB total traffic (~4 us).
// ---------------------------------------------------------------------------
__global__ __launch_bounds__(256) void transpose_v(
    const bf16* __restrict__ V, bf16* __restrict__ Vt)
{
    __shared__ bf16 sT[64 * 64];
    int tid = threadIdx.x;
    int bh = blockIdx.y;
    int st = blockIdx.x * 64;
    const bf16* Vb = V + ((size_t)bh * S_ + st) * DH_;
    bf16* Vo = Vt + (size_t)bh * DH_ * S_ + st;

#pragma unroll
    for (int i = 0; i < 2; i++) {
        int c = tid + i * 256;           // 0..511
        int s = c >> 3, dg = (c & 7) * 8;
        bf16x8 v = *(const bf16x8*)&Vb[(size_t)s * DH_ + dg];
        int g = dg >> 3;                 // swizzle key for rows d in [dg, dg+8)
#pragma unroll
        for (int j = 0; j < 8; j++)
            sT[(dg + j) * 64 + (s ^ (g * 8))] = v[j];
    }
    __syncthreads();
#pragma unroll
    for (int i = 0; i < 2; i++) {
        int c = tid + i * 256;
        int d = c >> 3, sgq = c & 7;
        int gg = d >> 3;
        bf16x8 v = *(const bf16x8*)&sT[d * 64 + ((sgq ^ gg) * 8)];
        *(bf16x8*)&Vo[(size_t)d * S_ + sgq * 8] = v;
    }
}

// ---------------------------------------------------------------------------
// Kernel 3 (R9 structure + R10 sP fix): flash attention, no max-tracking,
// S^T formulation. Block tile 128q x 128k/iter; 4 waves = 2 q-halves x 2
// key-halves, each 64q x 64k (two 32-key passes).
// R10: sP rows padded to 40 elems (80B = 20-bank rotation, 16B-aligned):
// write conflicts <=2-way (free), reads at b128 minimum; XOR key removed
// (R9's even-only X key caused 3.1e6 conflicts).
// grid (S/128, B*H) = 512 blocks = 2/CU, LDS ~61KB -> 2 blocks/CU.
// ---------------------------------------------------------------------------
__global__ __launch_bounds__(256, 2) void attn_kernel(
    const bf16* __restrict__ Q, const bf16* __restrict__ Kg,
    const bf16* __restrict__ Vt, const int* __restrict__ mask,
    bf16* __restrict__ Og)
{
    __shared__ __attribute__((aligned(16))) bf16 sK[128 * 64];   // [key][dh] 16KB
    __shared__ __attribute__((aligned(16))) bf16 sV[64 * 128];   // [d][key] 16KB
    __shared__ __attribute__((aligned(16))) bf16 sP[4][64 * 40]; // [q][key32] 20KB
    __shared__ float sMaddAll[S_];                               // 8KB
    __shared__ float sPsumR[128];
    __shared__ float sPsumF[128];

    int tid = threadIdx.x;
    int wave = tid >> 6, lane = tid & 63;
    int quad = lane >> 4, l16 = lane & 15;
    int bh = blockIdx.y;
    int b = bh >> 4;
    int q0 = blockIdx.x * 128;
    int f8 = l16 & 7;                          // sK read swizzle key
    int qh = wave & 1;                         // q-half (0/1)
    int kh = wave >> 1;                        // key-half (0/1)

    const bf16* Qb = Q + (size_t)bh * S_ * DH_;
    const bf16* Kb = Kg + (size_t)bh * S_ * DH_;
    const bf16* Vb = Vt + (size_t)bh * DH_ * S_;

    // expand mask row once per block: 0 -> -1e30, 1 -> 0
#pragma unroll
    for (int i = 0; i < S_ / 256; i++) {
        int idx = tid + i * 256;
        sMaddAll[idx] = mask[b * S_ + idx] ? 0.f : -1e30f;
    }

    // Q fragments for 4 q-tiles (B-operand; layout n=lane&15, k=quad*8+j)
    bf16x8 aq[4][2];
#pragma unroll
    for (int qt = 0; qt < 4; qt++) {
        int qrow = q0 + qh * 64 + qt * 16 + l16;
        aq[qt][0] = *(const bf16x8*)&Qb[(size_t)qrow * DH_ + quad * 8];
        aq[qt][1] = *(const bf16x8*)&Qb[(size_t)qrow * DH_ + 32 + quad * 8];
    }

    f32x4 o[4][4];                       // o[qt][dt], C row=q, col=d
#pragma unroll
    for (int i = 0; i < 4; i++)
#pragma unroll
        for (int j = 0; j < 4; j++) o[i][j] = (f32x4){0.f, 0.f, 0.f, 0.f};
    float psum[4] = {0.f, 0.f, 0.f, 0.f};   // per q=qt*16+l16, partial over keys

    for (int kt = 0; kt < S_; kt += 128) {
        // stage K[128k][64dh] + V^T[64d][128k]; source-col swizzled so the
        // lane-contiguous DMA dest gives conflict-free fragment reads.
#pragma unroll
        for (int i = 0; i < 8; i++) {
            int c = tid + i * 256;            // 0..2047
            if (c < 1024) {                   // K chunk: row=c>>3, group=c&7
                int row = c >> 3;
                int g = (c & 7) ^ (row & 7);
                gld_lds16(&Kb[(size_t)(kt + row) * DH_ + g * 8], &sK[c * 8]);
            } else {                          // V chunk: row=(c-1024)>>4, group=&15
                int cv = c - 1024;
                int row = cv >> 4;
                int g = (cv & 15) ^ (row & 15);
                gld_lds16(&Vb[(size_t)row * S_ + kt + g * 8], &sV[cv * 8]);
            }
        }
        WAIT_VMCNT0();
        __syncthreads();

#pragma unroll
        for (int pass = 0; pass < 2; pass++) {   // 32 keys per pass
            // --- S^T = K @ Q^T, P = exp2(S + maskadd), packed b64 stores ---
#pragma unroll
            for (int mtl = 0; mtl < 2; mtl++) {
                int keyrow = kh * 64 + pass * 32 + mtl * 16;   // wave-local tile base
                bf16x8 ak0 = *(const bf16x8*)&sK[(keyrow + l16) * 64 + (quad ^ f8) * 8];
                bf16x8 ak1 = *(const bf16x8*)&sK[(keyrow + l16) * 64 + ((quad + 4) ^ f8) * 8];
                float4 ma4 = *(const float4*)&sMaddAll[kt + keyrow + quad * 4];
#pragma unroll
                for (int qt = 0; qt < 4; qt++) {
                    f32x4 c = (f32x4){0.f, 0.f, 0.f, 0.f};
                    c = __builtin_amdgcn_mfma_f32_16x16x32_bf16(ak0, aq[qt][0], c, 0, 0, 0);
                    c = __builtin_amdgcn_mfma_f32_16x16x32_bf16(ak1, aq[qt][1], c, 0, 0, 0);
                    float p0 = __builtin_amdgcn_exp2f(c[0] + ma4.x);
                    float p1 = __builtin_amdgcn_exp2f(c[1] + ma4.y);
                    float p2 = __builtin_amdgcn_exp2f(c[2] + ma4.z);
                    float p3 = __builtin_amdgcn_exp2f(c[3] + ma4.w);
                    psum[qt] += (p0 + p1) + (p2 + p3);
                    bf16x4 pk = { f2bf(p0), f2bf(p1), f2bf(p2), f2bf(p3) };
                    // 4 consecutive keys (group mtl*4+quad) at q-row, padded rows
                    *(bf16x4*)&sP[wave][(qt * 16 + l16) * 40 + (mtl * 4 + quad) * 4] = pk;
                }
            }

            // --- O += P @ V (A=P[q][k32], B=V^T[d][k32]) ---
            WAIT_LGKM0();   // same-wave sP write -> read drain (R2 rule)
            bf16x8 ap[4];
#pragma unroll
            for (int qt = 0; qt < 4; qt++)
                ap[qt] = *(const bf16x8*)&sP[wave][(qt * 16 + l16) * 40 + quad * 8];
#pragma unroll
            for (int dt = 0; dt < 4; dt++) {
                int g = (kh * 8 + pass * 4 + quad) ^ l16;    // sV group slot
                bf16x8 bv = *(const bf16x8*)&sV[(dt * 16 + l16) * 128 + g * 8];
#pragma unroll
                for (int qt = 0; qt < 4; qt++)
                    o[qt][dt] = __builtin_amdgcn_mfma_f32_16x16x32_bf16(ap[qt], bv, o[qt][dt], 0, 0, 0);
            }
            // pass 1 overwrites sP[wave]: same-wave in-order DS pipe + the
            // lgkm waits before the consuming MFMAs make this safe.
        }
        __syncthreads();   // all fragment reads done before next staging
    }

    // reduce psum over quads (keys within the wave) -> full per-(q, key-half)
#pragma unroll
    for (int qt = 0; qt < 4; qt++) {
        float v = psum[qt];
        v += __shfl_xor(v, 16);
        v += __shfl_xor(v, 32);
        psum[qt] = v;
    }

    // cross-wave reduction: waves 2,3 (key-half 1) hand partials to waves 0,1.
    __syncthreads();
    float* sRed = (wave == 2) ? (float*)sK : (float*)sV;   // 16KB each
    if (wave >= 2) {
#pragma unroll
        for (int qt = 0; qt < 4; qt++)
#pragma unroll
            for (int dt = 0; dt < 4; dt++)
                *(f32x4*)&sRed[((qt * 4 + dt) * 64 + lane) * 4] = o[qt][dt];
#pragma unroll
        for (int qt = 0; qt < 4; qt++)
            sPsumR[(wave - 2) * 64 + qt * 16 + l16] = psum[qt];  // all quads same value
    }
    __syncthreads();
    if (wave < 2) {
        float* src = (wave == 0) ? (float*)sK : (float*)sV;
#pragma unroll
        for (int qt = 0; qt < 4; qt++)
#pragma unroll
            for (int dt = 0; dt < 4; dt++)
                o[qt][dt] += *(const f32x4*)&src[((qt * 4 + dt) * 64 + lane) * 4];
        // combined psum, then broadcast across quads via LDS (q index remap)
#pragma unroll
        for (int qt = 0; qt < 4; qt++) {
            float v = psum[qt] + sPsumR[wave * 64 + qt * 16 + l16];
            sPsumF[wave * 64 + qt * 16 + l16] = v;
        }
        WAIT_LGKM0();   // same-wave write -> read
        int h = bh & 15;
#pragma unroll
        for (int qt = 0; qt < 4; qt++) {
            float4 ps = *(const float4*)&sPsumF[wave * 64 + qt * 16 + quad * 4];
            float rcp[4] = { 1.f / ps.x, 1.f / ps.y, 1.f / ps.z, 1.f / ps.w };
#pragma unroll
            for (int r = 0; r < 4; r++) {
                int s = q0 + qh * 64 + qt * 16 + quad * 4 + r;
#pragma unroll
                for (int dt = 0; dt < 4; dt++) {
                    int d = dt * 16 + l16;
                    Og[((size_t)(b * S_ + s)) * D_ + h * 64 + d] = f2bf(o[qt][dt][r] * rcp[r]);
                }
            }
        }
    }
}

// ---------------------------------------------------------------------------
extern "C" void kernel_launch(void* const* d_in, const int* in_sizes, int n_in,
                              void* d_out, int out_size, void* d_ws, size_t ws_size,
                              hipStream_t stream) {
    const float* hs = (const float*)d_in[0];
    const int* mask = (const int*)d_in[1];
    const float* Wq = (const float*)d_in[2];
    const float* bq = (const float*)d_in[3];
    const float* Wk = (const float*)d_in[4];
    const float* bk = (const float*)d_in[5];
    const float* Wv = (const float*)d_in[6];
    const float* bv = (const float*)d_in[7];
    const float* Wo = (const float*)d_in[8];
    const float* bo = (const float*)d_in[9];
    float* out = (float*)d_out;

    char* ws = (char*)d_ws;
    bf16* hsb  = (bf16*)(ws);                          // 8 MB (4096x1024), dead after gemm0
    bf16* wqkv = (bf16*)(ws + ((size_t)8 << 20));      // 6 MB (3072x1024)
    bf16* wob  = (bf16*)(ws + ((size_t)14 << 20));     // 2 MB (1024x1024)
    bf16* Qw   = (bf16*)(ws + ((size_t)16 << 20));     // 8 MB (b,h,s,d)
    bf16* Kw   = (bf16*)(ws + ((size_t)24 << 20));     // 8 MB (b,h,s,d)
    bf16* Vw   = (bf16*)(ws + ((size_t)32 << 20));     // 8 MB (b,h,s,d)
    bf16* attn = (bf16*)(ws + ((size_t)40 << 20));     // 8 MB (b,s,h*64+d)
    bf16* Vtw  = (bf16*)(ws);                          // 8 MB (b,h,d,s), reuses hsb

    cvt_kernel<<<8192, 256, 0, stream>>>(hs, Wq, Wk, Wv, Wo, hsb, wqkv, wob);
    gemm_bt<<<dim3(32, 24), 256, 0, stream>>>(hsb, wqkv, 0, bq, bk, bv,
                                              Qw, Kw, Vw, nullptr);
    transpose_v<<<dim3(32, 32), 256, 0, stream>>>(Vw, Vtw);
    attn_kernel<<<dim3(16, 32), 256, 0, stream>>>(Qw, Kw, Vtw, mask, attn);
    gemm_bt<<<dim3(32, 8), 256, 0, stream>>>(attn, wob, 1, bo, nullptr, nullptr,
                                             nullptr, nullptr, nullptr, out);
}

// Round 11
// 205.876 us; speedup vs baseline: 1.0144x; 1.0144x over previous
//
#include <hip/hip_runtime.h>
#include <hip/hip_bf16.h>

typedef __bf16 bf16;
typedef __bf16 bf16x4 __attribute__((ext_vector_type(4)));
typedef __bf16 bf16x8 __attribute__((ext_vector_type(8)));
typedef float f32x4 __attribute__((ext_vector_type(4)));

#define B_ 2
#define S_ 2048
#define H_ 16
#define DH_ 64
#define D_ 1024
#define NT_ 4096  // B_*S_

// Ordering notes (R2 post-mortem): global_load_lds retires on vmcnt, ds_* on
// lgkmcnt. Two edges MUST be explicit:
//   (1) vmcnt(0) before the barrier that publishes freshly staged LDS tiles.
//   (2) lgkmcnt(0) between a wave's own ds_write and its ds_read of the same
//       bytes (sP round-trip, psum broadcast).
// R6+R8: explicit double-buffering regressed twice — implicit TLP at 8+
// waves/CU already hides staging latency. R10: separate transpose kernel
// cost more than the "bad" V^T epilogue scatter it replaced (scatter writes
// are buffered/overlapped) — reverted.
#define WAIT_VMCNT0() asm volatile("s_waitcnt vmcnt(0)" ::: "memory")
#define WAIT_LGKM0()  asm volatile("s_waitcnt lgkmcnt(0)" ::: "memory")

// async global->LDS, 16B per lane; LDS dest is wave-uniform base + lane*16
__device__ __forceinline__ void gld_lds16(const bf16* g, bf16* l) {
    __builtin_amdgcn_global_load_lds(
        (__attribute__((address_space(1))) void*)g,
        (__attribute__((address_space(3))) void*)l, 16, 0, 0);
}

// fast RNE float->bf16, no NaN/denorm path (inputs are finite, well-scaled)
__device__ __forceinline__ bf16 f2bf(float x) {
    union { float f; unsigned u; } v; v.f = x;
    unsigned short h = (unsigned short)((v.u + 0x7FFF + ((v.u >> 16) & 1)) >> 16);
    return __builtin_bit_cast(bf16, h);
}

// ---------------------------------------------------------------------------
// Kernel 1: fp32 -> bf16 conversion/packing.
// layout: [hs 4194304][Wq|Wk|Wv 3145728][Wo 1048576], 4 elems/thread
// ---------------------------------------------------------------------------
__global__ __launch_bounds__(256) void cvt_kernel(
    const float* __restrict__ hs,
    const float* __restrict__ Wq, const float* __restrict__ Wk,
    const float* __restrict__ Wv, const float* __restrict__ Wo,
    bf16* __restrict__ hsb, bf16* __restrict__ wqkv, bf16* __restrict__ wob)
{
    int i = (blockIdx.x * 256 + threadIdx.x) * 4;
    const float* src;
    bf16* dst;
    if (i < 4194304) {
        src = hs + i; dst = hsb + i;
    } else if (i < 7340032) {
        int off = i - 4194304;
        int which = off >> 20;           // 0=Wq 1=Wk 2=Wv
        int within = off & 1048575;
        src = (which == 0 ? Wq : which == 1 ? Wk : Wv) + within;
        dst = wqkv + off;
    } else {
        int off = i - 7340032;
        src = Wo + off; dst = wob + off;
    }
    float4 v = *(const float4*)src;
    bf16x4 o = { (bf16)v.x, (bf16)v.y, (bf16)v.z, (bf16)v.w };
    *(bf16x4*)dst = o;
}

// ---------------------------------------------------------------------------
// Kernel 2/4: C = A @ B^T (+bias).  A: MxK bf16 row-major, B: NxK bf16 row-major.
// 128x128 tile, 4 waves, 4x4 mfma 16x16x32 each.
// R11: BK=64 (two k-phases per staged tile): halves barrier rounds (32->16
// for K=1024) and doubles MFMA per publish (32/round) — the short-K loop was
// barrier/staging-issue dominated at BK=32. LDS 32KB; launch_bounds(256,3)
// keeps 3 blocks/CU (96KB < 160KB), so gemm0's 768 blocks = one round.
// 64-elem LDS rows swizzled f=row&7 (same structure as attn sK: measured 0
// conflicts). V epilogue: fused (b,h,d,s) scatter (R10 showed it beats a
// separate transpose kernel).
// mode 0: QKV epilogue -> Q(xscale)/K to (b,h,s,d), V^T to (b,h,d,s), bf16
// mode 1: out epilogue -> fp32 row-major + bias
// ---------------------------------------------------------------------------
__global__ __launch_bounds__(256, 3) void gemm_bt(
    const bf16* __restrict__ A, const bf16* __restrict__ Bm,
    int mode,
    const float* __restrict__ b0, const float* __restrict__ b1,
    const float* __restrict__ b2,
    bf16* __restrict__ Qo, bf16* __restrict__ Ko, bf16* __restrict__ Vt,
    float* __restrict__ Co)
{
    const int K = 1024;
    __shared__ __attribute__((aligned(16))) bf16 sA[128 * 64];   // 16KB
    __shared__ __attribute__((aligned(16))) bf16 sB[128 * 64];   // 16KB

    int tid = threadIdx.x;
    int wave = tid >> 6, lane = tid & 63;
    int quad = lane >> 4, l16 = lane & 15;
    int m0 = blockIdx.x * 128;
    int n0 = blockIdx.y * 128;
    int wm = (wave & 1) * 64, wn = (wave >> 1) * 64;
    int fs = l16 & 7;                   // read-side swizzle key (row&7 == l16&7)

    f32x4 acc[4][4];
#pragma unroll
    for (int i = 0; i < 4; i++)
#pragma unroll
        for (int j = 0; j < 4; j++) acc[i][j] = (f32x4){0.f, 0.f, 0.f, 0.f};

    for (int k0 = 0; k0 < K; k0 += 64) {
#pragma unroll
        for (int i = 0; i < 4; i++) {
            int c = tid + i * 256;          // 0..1023, 16B each
            int row = c >> 3;               // 8 chunks per 64-elem row
            int kc = ((c & 7) ^ (row & 7)) * 8;   // swizzled source group
            gld_lds16(A + (size_t)(m0 + row) * K + k0 + kc, &sA[c * 8]);
            gld_lds16(Bm + (size_t)(n0 + row) * K + k0 + kc, &sB[c * 8]);
        }
        WAIT_VMCNT0();          // async LDS writes landed before barrier
        __syncthreads();

#pragma unroll
        for (int kp = 0; kp < 2; kp++) {     // two 32-col k-windows
            bf16x8 af[4], bfr[4];
#pragma unroll
            for (int i = 0; i < 4; i++)
                af[i] = *(const bf16x8*)&sA[(wm + i * 16 + l16) * 64 + (((kp * 4 + quad) ^ fs) * 8)];
#pragma unroll
            for (int j = 0; j < 4; j++)
                bfr[j] = *(const bf16x8*)&sB[(wn + j * 16 + l16) * 64 + (((kp * 4 + quad) ^ fs) * 8)];
#pragma unroll
            for (int i = 0; i < 4; i++)
#pragma unroll
                for (int j = 0; j < 4; j++)
                    acc[i][j] = __builtin_amdgcn_mfma_f32_16x16x32_bf16(
                        af[i], bfr[j], acc[i][j], 0, 0, 0);
        }
        // ds_read->MFMA operand deps retire reads before any wave re-stages
        __syncthreads();
    }

    // C/D layout: col = lane&15, row = quad*4 + reg  (m89/m91 verified)
    if (mode == 0) {
        const float QSCALE = 0.125f * 1.44269504088896340736f;  // 1/sqrt(64)*log2(e)
#pragma unroll
        for (int j = 0; j < 4; j++) {
            int n = n0 + wn + j * 16 + l16;
            int region = n >> 10;            // block-uniform (n0 128-aligned)
            int nn = n & 1023;
            int h = nn >> 6, d = nn & 63;
            float bias = (region == 0 ? b0 : region == 1 ? b1 : b2)[nn];
#pragma unroll
            for (int i = 0; i < 4; i++)
#pragma unroll
                for (int r = 0; r < 4; r++) {
                    int m = m0 + wm + i * 16 + quad * 4 + r;
                    int b = m >> 11, s = m & 2047;
                    int bh = b * H_ + h;
                    float v = acc[i][j][r] + bias;
                    if (region == 0)
                        Qo[((size_t)bh * S_ + s) * DH_ + d] = f2bf(v * QSCALE);
                    else if (region == 1)
                        Ko[((size_t)bh * S_ + s) * DH_ + d] = f2bf(v);
                    else
                        Vt[((size_t)bh * DH_ + d) * S_ + s] = f2bf(v);  // fused V^T
                }
        }
    } else {
#pragma unroll
        for (int j = 0; j < 4; j++) {
            int n = n0 + wn + j * 16 + l16;
            float bias = b0[n];
#pragma unroll
            for (int i = 0; i < 4; i++)
#pragma unroll
                for (int r = 0; r < 4; r++) {
                    int m = m0 + wm + i * 16 + quad * 4 + r;
                    Co[(size_t)m * D_ + n] = acc[i][j][r] + bias;
                }
        }
    }
}

// ---------------------------------------------------------------------------
// Kernel 3 (unchanged from R10): flash attention, no max-tracking, S^T form.
// Block tile 128q x 128k/iter; 4 waves = 2 q-halves x 2 key-halves.
// sP rows padded to 40 elems. Known: 3.1e6 bank-conflict cycles remain
// (source not sP — unidentified, ~2-3us; deprioritized).
// grid (S/128, B*H) = 512 blocks = 2/CU.
// ---------------------------------------------------------------------------
__global__ __launch_bounds__(256, 2) void attn_kernel(
    const bf16* __restrict__ Q, const bf16* __restrict__ Kg,
    const bf16* __restrict__ Vt, const int* __restrict__ mask,
    bf16* __restrict__ Og)
{
    __shared__ __attribute__((aligned(16))) bf16 sK[128 * 64];   // [key][dh] 16KB
    __shared__ __attribute__((aligned(16))) bf16 sV[64 * 128];   // [d][key] 16KB
    __shared__ __attribute__((aligned(16))) bf16 sP[4][64 * 40]; // [q][key32] 20KB
    __shared__ float sMaddAll[S_];                               // 8KB
    __shared__ float sPsumR[128];
    __shared__ float sPsumF[128];

    int tid = threadIdx.x;
    int wave = tid >> 6, lane = tid & 63;
    int quad = lane >> 4, l16 = lane & 15;
    int bh = blockIdx.y;
    int b = bh >> 4;
    int q0 = blockIdx.x * 128;
    int f8 = l16 & 7;                          // sK read swizzle key
    int qh = wave & 1;                         // q-half (0/1)
    int kh = wave >> 1;                        // key-half (0/1)

    const bf16* Qb = Q + (size_t)bh * S_ * DH_;
    const bf16* Kb = Kg + (size_t)bh * S_ * DH_;
    const bf16* Vb = Vt + (size_t)bh * DH_ * S_;

    // expand mask row once per block: 0 -> -1e30, 1 -> 0
#pragma unroll
    for (int i = 0; i < S_ / 256; i++) {
        int idx = tid + i * 256;
        sMaddAll[idx] = mask[b * S_ + idx] ? 0.f : -1e30f;
    }

    // Q fragments for 4 q-tiles (B-operand; layout n=lane&15, k=quad*8+j)
    bf16x8 aq[4][2];
#pragma unroll
    for (int qt = 0; qt < 4; qt++) {
        int qrow = q0 + qh * 64 + qt * 16 + l16;
        aq[qt][0] = *(const bf16x8*)&Qb[(size_t)qrow * DH_ + quad * 8];
        aq[qt][1] = *(const bf16x8*)&Qb[(size_t)qrow * DH_ + 32 + quad * 8];
    }

    f32x4 o[4][4];                       // o[qt][dt], C row=q, col=d
#pragma unroll
    for (int i = 0; i < 4; i++)
#pragma unroll
        for (int j = 0; j < 4; j++) o[i][j] = (f32x4){0.f, 0.f, 0.f, 0.f};
    float psum[4] = {0.f, 0.f, 0.f, 0.f};   // per q=qt*16+l16, partial over keys

    for (int kt = 0; kt < S_; kt += 128) {
        // stage K[128k][64dh] + V^T[64d][128k]; source-col swizzled so the
        // lane-contiguous DMA dest gives conflict-free fragment reads.
#pragma unroll
        for (int i = 0; i < 8; i++) {
            int c = tid + i * 256;            // 0..2047
            if (c < 1024) {                   // K chunk: row=c>>3, group=c&7
                int row = c >> 3;
                int g = (c & 7) ^ (row & 7);
                gld_lds16(&Kb[(size_t)(kt + row) * DH_ + g * 8], &sK[c * 8]);
            } else {                          // V chunk: row=(c-1024)>>4, group=&15
                int cv = c - 1024;
                int row = cv >> 4;
                int g = (cv & 15) ^ (row & 15);
                gld_lds16(&Vb[(size_t)row * S_ + kt + g * 8], &sV[cv * 8]);
            }
        }
        WAIT_VMCNT0();
        __syncthreads();

#pragma unroll
        for (int pass = 0; pass < 2; pass++) {   // 32 keys per pass
            // --- S^T = K @ Q^T, P = exp2(S + maskadd), packed b64 stores ---
#pragma unroll
            for (int mtl = 0; mtl < 2; mtl++) {
                int keyrow = kh * 64 + pass * 32 + mtl * 16;   // wave-local tile base
                bf16x8 ak0 = *(const bf16x8*)&sK[(keyrow + l16) * 64 + (quad ^ f8) * 8];
                bf16x8 ak1 = *(const bf16x8*)&sK[(keyrow + l16) * 64 + ((quad + 4) ^ f8) * 8];
                float4 ma4 = *(const float4*)&sMaddAll[kt + keyrow + quad * 4];
#pragma unroll
                for (int qt = 0; qt < 4; qt++) {
                    f32x4 c = (f32x4){0.f, 0.f, 0.f, 0.f};
                    c = __builtin_amdgcn_mfma_f32_16x16x32_bf16(ak0, aq[qt][0], c, 0, 0, 0);
                    c = __builtin_amdgcn_mfma_f32_16x16x32_bf16(ak1, aq[qt][1], c, 0, 0, 0);
                    float p0 = __builtin_amdgcn_exp2f(c[0] + ma4.x);
                    float p1 = __builtin_amdgcn_exp2f(c[1] + ma4.y);
                    float p2 = __builtin_amdgcn_exp2f(c[2] + ma4.z);
                    float p3 = __builtin_amdgcn_exp2f(c[3] + ma4.w);
                    psum[qt] += (p0 + p1) + (p2 + p3);
                    bf16x4 pk = { f2bf(p0), f2bf(p1), f2bf(p2), f2bf(p3) };
                    *(bf16x4*)&sP[wave][(qt * 16 + l16) * 40 + (mtl * 4 + quad) * 4] = pk;
                }
            }

            // --- O += P @ V (A=P[q][k32], B=V^T[d][k32]) ---
            WAIT_LGKM0();   // same-wave sP write -> read drain (R2 rule)
            bf16x8 ap[4];
#pragma unroll
            for (int qt = 0; qt < 4; qt++)
                ap[qt] = *(const bf16x8*)&sP[wave][(qt * 16 + l16) * 40 + quad * 8];
#pragma unroll
            for (int dt = 0; dt < 4; dt++) {
                int g = (kh * 8 + pass * 4 + quad) ^ l16;    // sV group slot
                bf16x8 bv = *(const bf16x8*)&sV[(dt * 16 + l16) * 128 + g * 8];
#pragma unroll
                for (int qt = 0; qt < 4; qt++)
                    o[qt][dt] = __builtin_amdgcn_mfma_f32_16x16x32_bf16(ap[qt], bv, o[qt][dt], 0, 0, 0);
            }
        }
        __syncthreads();   // all fragment reads done before next staging
    }

    // reduce psum over quads (keys within the wave) -> full per-(q, key-half)
#pragma unroll
    for (int qt = 0; qt < 4; qt++) {
        float v = psum[qt];
        v += __shfl_xor(v, 16);
        v += __shfl_xor(v, 32);
        psum[qt] = v;
    }

    // cross-wave reduction: waves 2,3 (key-half 1) hand partials to waves 0,1.
    __syncthreads();
    float* sRed = (wave == 2) ? (float*)sK : (float*)sV;   // 16KB each
    if (wave >= 2) {
#pragma unroll
        for (int qt = 0; qt < 4; qt++)
#pragma unroll
            for (int dt = 0; dt < 4; dt++)
                *(f32x4*)&sRed[((qt * 4 + dt) * 64 + lane) * 4] = o[qt][dt];
#pragma unroll
        for (int qt = 0; qt < 4; qt++)
            sPsumR[(wave - 2) * 64 + qt * 16 + l16] = psum[qt];  // all quads same value
    }
    __syncthreads();
    if (wave < 2) {
        float* src = (wave == 0) ? (float*)sK : (float*)sV;
#pragma unroll
        for (int qt = 0; qt < 4; qt++)
#pragma unroll
            for (int dt = 0; dt < 4; dt++)
                o[qt][dt] += *(const f32x4*)&src[((qt * 4 + dt) * 64 + lane) * 4];
        // combined psum, then broadcast across quads via LDS (q index remap)
#pragma unroll
        for (int qt = 0; qt < 4; qt++) {
            float v = psum[qt] + sPsumR[wave * 64 + qt * 16 + l16];
            sPsumF[wave * 64 + qt * 16 + l16] = v;
        }
        WAIT_LGKM0();   // same-wave write -> read
        int h = bh & 15;
#pragma unroll
        for (int qt = 0; qt < 4; qt++) {
            float4 ps = *(const float4*)&sPsumF[wave * 64 + qt * 16 + quad * 4];
            float rcp[4] = { 1.f / ps.x, 1.f / ps.y, 1.f / ps.z, 1.f / ps.w };
#pragma unroll
            for (int r = 0; r < 4; r++) {
                int s = q0 + qh * 64 + qt * 16 + quad * 4 + r;
#pragma unroll
                for (int dt = 0; dt < 4; dt++) {
                    int d = dt * 16 + l16;
                    Og[((size_t)(b * S_ + s)) * D_ + h * 64 + d] = f2bf(o[qt][dt][r] * rcp[r]);
                }
            }
        }
    }
}

// ---------------------------------------------------------------------------
extern "C" void kernel_launch(void* const* d_in, const int* in_sizes, int n_in,
                              void* d_out, int out_size, void* d_ws, size_t ws_size,
                              hipStream_t stream) {
    const float* hs = (const float*)d_in[0];
    const int* mask = (const int*)d_in[1];
    const float* Wq = (const float*)d_in[2];
    const float* bq = (const float*)d_in[3];
    const float* Wk = (const float*)d_in[4];
    const float* bk = (const float*)d_in[5];
    const float* Wv = (const float*)d_in[6];
    const float* bv = (const float*)d_in[7];
    const float* Wo = (const float*)d_in[8];
    const float* bo = (const float*)d_in[9];
    float* out = (float*)d_out;

    char* ws = (char*)d_ws;
    bf16* hsb  = (bf16*)(ws);                          // 8 MB (4096x1024)
    bf16* wqkv = (bf16*)(ws + ((size_t)8 << 20));      // 6 MB (3072x1024)
    bf16* wob  = (bf16*)(ws + ((size_t)14 << 20));     // 2 MB (1024x1024)
    bf16* Qw   = (bf16*)(ws + ((size_t)16 << 20));     // 8 MB (b,h,s,d)
    bf16* Kw   = (bf16*)(ws + ((size_t)24 << 20));     // 8 MB (b,h,s,d)
    bf16* Vtw  = (bf16*)(ws + ((size_t)32 << 20));     // 8 MB (b,h,d,s)
    bf16* attn = (bf16*)(ws + ((size_t)40 << 20));     // 8 MB (b,s,h*64+d)

    cvt_kernel<<<8192, 256, 0, stream>>>(hs, Wq, Wk, Wv, Wo, hsb, wqkv, wob);
    gemm_bt<<<dim3(32, 24), 256, 0, stream>>>(hsb, wqkv, 0, bq, bk, bv,
                                              Qw, Kw, Vtw, nullptr);
    attn_kernel<<<dim3(16, 32), 256, 0, stream>>>(Qw, Kw, Vtw, mask, attn);
    gemm_bt<<<dim3(32, 8), 256, 0, stream>>>(attn, wob, 1, bo, nullptr, nullptr,
                                             nullptr, nullptr, nullptr, out);
}

// Round 12
// 197.010 us; speedup vs baseline: 1.0600x; 1.0450x over previous
//
#include <hip/hip_runtime.h>
#include <hip/hip_bf16.h>

typedef __bf16 bf16;
typedef __bf16 bf16x4 __attribute__((ext_vector_type(4)));
typedef __bf16 bf16x8 __attribute__((ext_vector_type(8)));
typedef float f32x4 __attribute__((ext_vector_type(4)));

#define B_ 2
#define S_ 2048
#define H_ 16
#define DH_ 64
#define D_ 1024
#define NT_ 4096  // B_*S_

// Ordering notes (R2 post-mortem): global_load_lds retires on vmcnt, ds_* on
// lgkmcnt. Two edges MUST be explicit:
//   (1) vmcnt(0) before the barrier that publishes freshly staged LDS tiles.
//   (2) lgkmcnt(0) between a wave's own ds_write and its ds_read of the same
//       bytes (sP round-trip, psum broadcast).
// R6+R8: explicit double-buffering regressed twice — implicit TLP at 8+
// waves/CU already hides staging latency.
#define WAIT_VMCNT0() asm volatile("s_waitcnt vmcnt(0)" ::: "memory")
#define WAIT_LGKM0()  asm volatile("s_waitcnt lgkmcnt(0)" ::: "memory")

// async global->LDS, 16B per lane; LDS dest is wave-uniform base + lane*16
__device__ __forceinline__ void gld_lds16(const bf16* g, bf16* l) {
    __builtin_amdgcn_global_load_lds(
        (__attribute__((address_space(1))) void*)g,
        (__attribute__((address_space(3))) void*)l, 16, 0, 0);
}

// fast RNE float->bf16, no NaN/denorm path (inputs are finite, well-scaled)
__device__ __forceinline__ bf16 f2bf(float x) {
    union { float f; unsigned u; } v; v.f = x;
    unsigned short h = (unsigned short)((v.u + 0x7FFF + ((v.u >> 16) & 1)) >> 16);
    return __builtin_bit_cast(bf16, h);
}

// ---------------------------------------------------------------------------
// Kernel 1: fp32 -> bf16 conversion/packing.
// layout: [hs 4194304][Wq|Wk|Wv 3145728][Wo 1048576], 4 elems/thread
// ---------------------------------------------------------------------------
__global__ __launch_bounds__(256) void cvt_kernel(
    const float* __restrict__ hs,
    const float* __restrict__ Wq, const float* __restrict__ Wk,
    const float* __restrict__ Wv, const float* __restrict__ Wo,
    bf16* __restrict__ hsb, bf16* __restrict__ wqkv, bf16* __restrict__ wob)
{
    int i = (blockIdx.x * 256 + threadIdx.x) * 4;
    const float* src;
    bf16* dst;
    if (i < 4194304) {
        src = hs + i; dst = hsb + i;
    } else if (i < 7340032) {
        int off = i - 4194304;
        int which = off >> 20;           // 0=Wq 1=Wk 2=Wv
        int within = off & 1048575;
        src = (which == 0 ? Wq : which == 1 ? Wk : Wv) + within;
        dst = wqkv + off;
    } else {
        int off = i - 7340032;
        src = Wo + off; dst = wob + off;
    }
    float4 v = *(const float4*)src;
    bf16x4 o = { (bf16)v.x, (bf16)v.y, (bf16)v.z, (bf16)v.w };
    *(bf16x4*)dst = o;
}

// ---------------------------------------------------------------------------
// Kernel 2: QKV projection. C = A @ B^T (+bias). 128x128 tile, BK=64,
// 4 waves, 4x4 mfma 16x16x32. lb(256,3): all 768 blocks co-resident.
// R12: V^T stores packed as bf16x4 — acc regs r=0..3 are 4 CONSECUTIVE s at
// fixed d, so one b64 store replaces 4 scalar 2B stores at 4KB stride
// (write amplification 16x -> 4x on the 8MB V output).
// mode 0 only now (out projection moved to gemm_out).
// ---------------------------------------------------------------------------
__global__ __launch_bounds__(256, 3) void gemm_bt(
    const bf16* __restrict__ A, const bf16* __restrict__ Bm,
    const float* __restrict__ b0, const float* __restrict__ b1,
    const float* __restrict__ b2,
    bf16* __restrict__ Qo, bf16* __restrict__ Ko, bf16* __restrict__ Vt)
{
    const int K = 1024;
    __shared__ __attribute__((aligned(16))) bf16 sA[128 * 64];   // 16KB
    __shared__ __attribute__((aligned(16))) bf16 sB[128 * 64];   // 16KB

    int tid = threadIdx.x;
    int wave = tid >> 6, lane = tid & 63;
    int quad = lane >> 4, l16 = lane & 15;
    int m0 = blockIdx.x * 128;
    int n0 = blockIdx.y * 128;
    int wm = (wave & 1) * 64, wn = (wave >> 1) * 64;
    int fs = l16 & 7;                   // read-side swizzle key (row&7 == l16&7)

    f32x4 acc[4][4];
#pragma unroll
    for (int i = 0; i < 4; i++)
#pragma unroll
        for (int j = 0; j < 4; j++) acc[i][j] = (f32x4){0.f, 0.f, 0.f, 0.f};

    for (int k0 = 0; k0 < K; k0 += 64) {
#pragma unroll
        for (int i = 0; i < 4; i++) {
            int c = tid + i * 256;          // 0..1023, 16B each
            int row = c >> 3;               // 8 chunks per 64-elem row
            int kc = ((c & 7) ^ (row & 7)) * 8;   // swizzled source group
            gld_lds16(A + (size_t)(m0 + row) * K + k0 + kc, &sA[c * 8]);
            gld_lds16(Bm + (size_t)(n0 + row) * K + k0 + kc, &sB[c * 8]);
        }
        WAIT_VMCNT0();          // async LDS writes landed before barrier
        __syncthreads();

#pragma unroll
        for (int kp = 0; kp < 2; kp++) {     // two 32-col k-windows
            bf16x8 af[4], bfr[4];
#pragma unroll
            for (int i = 0; i < 4; i++)
                af[i] = *(const bf16x8*)&sA[(wm + i * 16 + l16) * 64 + (((kp * 4 + quad) ^ fs) * 8)];
#pragma unroll
            for (int j = 0; j < 4; j++)
                bfr[j] = *(const bf16x8*)&sB[(wn + j * 16 + l16) * 64 + (((kp * 4 + quad) ^ fs) * 8)];
#pragma unroll
            for (int i = 0; i < 4; i++)
#pragma unroll
                for (int j = 0; j < 4; j++)
                    acc[i][j] = __builtin_amdgcn_mfma_f32_16x16x32_bf16(
                        af[i], bfr[j], acc[i][j], 0, 0, 0);
        }
        __syncthreads();
    }

    // C/D layout: col = lane&15, row = quad*4 + reg  (m89/m91 verified)
    const float QSCALE = 0.125f * 1.44269504088896340736f;  // 1/sqrt(64)*log2(e)
#pragma unroll
    for (int j = 0; j < 4; j++) {
        int n = n0 + wn + j * 16 + l16;
        int region = n >> 10;            // block-uniform (n0 128-aligned)
        int nn = n & 1023;
        int h = nn >> 6, d = nn & 63;
        float bias = (region == 0 ? b0 : region == 1 ? b1 : b2)[nn];
#pragma unroll
        for (int i = 0; i < 4; i++) {
            int mb = m0 + wm + i * 16 + quad * 4;     // 4-aligned, no 2048-cross
            int b = mb >> 11, s = mb & 2047;
            int bh = b * H_ + h;
            if (region == 2) {
                // packed V^T store: 4 consecutive s at fixed d (b64)
                bf16x4 pk = { f2bf(acc[i][j][0] + bias), f2bf(acc[i][j][1] + bias),
                              f2bf(acc[i][j][2] + bias), f2bf(acc[i][j][3] + bias) };
                *(bf16x4*)&Vt[((size_t)bh * DH_ + d) * S_ + s] = pk;
            } else {
#pragma unroll
                for (int r = 0; r < 4; r++) {
                    float v = acc[i][j][r] + bias;
                    if (region == 0)
                        Qo[((size_t)bh * S_ + s + r) * DH_ + d] = f2bf(v * QSCALE);
                    else
                        Ko[((size_t)bh * S_ + s + r) * DH_ + d] = f2bf(v);
                }
            }
        }
    }
}

// ---------------------------------------------------------------------------
// Kernel 4 (R12): out = attn @ Wo^T + bo. 128m x 64n tile, BK=64.
// Grid (32,16) = 512 blocks = 2/CU, 8 waves/CU (old 128x128 tile gave 256
// blocks = 1 block/CU = 4 waves/CU, latency-exposed tail).
// 4 waves as 2x2 -> each 64m x 32n (4x2 acc). Same swizzle as gemm_bt.
// ---------------------------------------------------------------------------
__global__ __launch_bounds__(256, 2) void gemm_out(
    const bf16* __restrict__ A, const bf16* __restrict__ Bm,
    const float* __restrict__ bias0, float* __restrict__ Co)
{
    const int K = 1024;
    __shared__ __attribute__((aligned(16))) bf16 sA[128 * 64];   // 16KB
    __shared__ __attribute__((aligned(16))) bf16 sB[64 * 64];    // 8KB

    int tid = threadIdx.x;
    int wave = tid >> 6, lane = tid & 63;
    int quad = lane >> 4, l16 = lane & 15;
    int m0 = blockIdx.x * 128;
    int n0 = blockIdx.y * 64;
    int wm = (wave & 1) * 64, wn = (wave >> 1) * 32;
    int fs = l16 & 7;

    f32x4 acc[4][2];
#pragma unroll
    for (int i = 0; i < 4; i++)
#pragma unroll
        for (int j = 0; j < 2; j++) acc[i][j] = (f32x4){0.f, 0.f, 0.f, 0.f};

    for (int k0 = 0; k0 < K; k0 += 64) {
#pragma unroll
        for (int i = 0; i < 4; i++) {        // A: 1024 chunks
            int c = tid + i * 256;
            int row = c >> 3;
            int kc = ((c & 7) ^ (row & 7)) * 8;
            gld_lds16(A + (size_t)(m0 + row) * K + k0 + kc, &sA[c * 8]);
        }
#pragma unroll
        for (int i = 0; i < 2; i++) {        // B: 512 chunks
            int c = tid + i * 256;
            int row = c >> 3;
            int kc = ((c & 7) ^ (row & 7)) * 8;
            gld_lds16(Bm + (size_t)(n0 + row) * K + k0 + kc, &sB[c * 8]);
        }
        WAIT_VMCNT0();
        __syncthreads();

#pragma unroll
        for (int kp = 0; kp < 2; kp++) {
            bf16x8 af[4], bfr[2];
#pragma unroll
            for (int i = 0; i < 4; i++)
                af[i] = *(const bf16x8*)&sA[(wm + i * 16 + l16) * 64 + (((kp * 4 + quad) ^ fs) * 8)];
#pragma unroll
            for (int j = 0; j < 2; j++)
                bfr[j] = *(const bf16x8*)&sB[(wn + j * 16 + l16) * 64 + (((kp * 4 + quad) ^ fs) * 8)];
#pragma unroll
            for (int i = 0; i < 4; i++)
#pragma unroll
                for (int j = 0; j < 2; j++)
                    acc[i][j] = __builtin_amdgcn_mfma_f32_16x16x32_bf16(
                        af[i], bfr[j], acc[i][j], 0, 0, 0);
        }
        __syncthreads();
    }

#pragma unroll
    for (int j = 0; j < 2; j++) {
        int n = n0 + wn + j * 16 + l16;
        float bias = bias0[n];
#pragma unroll
        for (int i = 0; i < 4; i++)
#pragma unroll
            for (int r = 0; r < 4; r++) {
                int m = m0 + wm + i * 16 + quad * 4 + r;
                Co[(size_t)m * D_ + n] = acc[i][j][r] + bias;
            }
    }
}

// ---------------------------------------------------------------------------
// Kernel 3 (unchanged from R11): flash attention, no max-tracking, S^T form.
// Block tile 128q x 128k/iter; 4 waves = 2 q-halves x 2 key-halves.
// sP rows padded to 40 elems. Known: 3.1e6 bank-conflict cycles remain
// (source unidentified, ~2-3us; deprioritized).
// grid (S/128, B*H) = 512 blocks = 2/CU.
// ---------------------------------------------------------------------------
__global__ __launch_bounds__(256, 2) void attn_kernel(
    const bf16* __restrict__ Q, const bf16* __restrict__ Kg,
    const bf16* __restrict__ Vt, const int* __restrict__ mask,
    bf16* __restrict__ Og)
{
    __shared__ __attribute__((aligned(16))) bf16 sK[128 * 64];   // [key][dh] 16KB
    __shared__ __attribute__((aligned(16))) bf16 sV[64 * 128];   // [d][key] 16KB
    __shared__ __attribute__((aligned(16))) bf16 sP[4][64 * 40]; // [q][key32] 20KB
    __shared__ float sMaddAll[S_];                               // 8KB
    __shared__ float sPsumR[128];
    __shared__ float sPsumF[128];

    int tid = threadIdx.x;
    int wave = tid >> 6, lane = tid & 63;
    int quad = lane >> 4, l16 = lane & 15;
    int bh = blockIdx.y;
    int b = bh >> 4;
    int q0 = blockIdx.x * 128;
    int f8 = l16 & 7;                          // sK read swizzle key
    int qh = wave & 1;                         // q-half (0/1)
    int kh = wave >> 1;                        // key-half (0/1)

    const bf16* Qb = Q + (size_t)bh * S_ * DH_;
    const bf16* Kb = Kg + (size_t)bh * S_ * DH_;
    const bf16* Vb = Vt + (size_t)bh * DH_ * S_;

    // expand mask row once per block: 0 -> -1e30, 1 -> 0
#pragma unroll
    for (int i = 0; i < S_ / 256; i++) {
        int idx = tid + i * 256;
        sMaddAll[idx] = mask[b * S_ + idx] ? 0.f : -1e30f;
    }

    // Q fragments for 4 q-tiles (B-operand; layout n=lane&15, k=quad*8+j)
    bf16x8 aq[4][2];
#pragma unroll
    for (int qt = 0; qt < 4; qt++) {
        int qrow = q0 + qh * 64 + qt * 16 + l16;
        aq[qt][0] = *(const bf16x8*)&Qb[(size_t)qrow * DH_ + quad * 8];
        aq[qt][1] = *(const bf16x8*)&Qb[(size_t)qrow * DH_ + 32 + quad * 8];
    }

    f32x4 o[4][4];                       // o[qt][dt], C row=q, col=d
#pragma unroll
    for (int i = 0; i < 4; i++)
#pragma unroll
        for (int j = 0; j < 4; j++) o[i][j] = (f32x4){0.f, 0.f, 0.f, 0.f};
    float psum[4] = {0.f, 0.f, 0.f, 0.f};   // per q=qt*16+l16, partial over keys

    for (int kt = 0; kt < S_; kt += 128) {
        // stage K[128k][64dh] + V^T[64d][128k]; source-col swizzled so the
        // lane-contiguous DMA dest gives conflict-free fragment reads.
#pragma unroll
        for (int i = 0; i < 8; i++) {
            int c = tid + i * 256;            // 0..2047
            if (c < 1024) {                   // K chunk: row=c>>3, group=c&7
                int row = c >> 3;
                int g = (c & 7) ^ (row & 7);
                gld_lds16(&Kb[(size_t)(kt + row) * DH_ + g * 8], &sK[c * 8]);
            } else {                          // V chunk: row=(c-1024)>>4, group=&15
                int cv = c - 1024;
                int row = cv >> 4;
                int g = (cv & 15) ^ (row & 15);
                gld_lds16(&Vb[(size_t)row * S_ + kt + g * 8], &sV[cv * 8]);
            }
        }
        WAIT_VMCNT0();
        __syncthreads();

#pragma unroll
        for (int pass = 0; pass < 2; pass++) {   // 32 keys per pass
            // --- S^T = K @ Q^T, P = exp2(S + maskadd), packed b64 stores ---
#pragma unroll
            for (int mtl = 0; mtl < 2; mtl++) {
                int keyrow = kh * 64 + pass * 32 + mtl * 16;   // wave-local tile base
                bf16x8 ak0 = *(const bf16x8*)&sK[(keyrow + l16) * 64 + (quad ^ f8) * 8];
                bf16x8 ak1 = *(const bf16x8*)&sK[(keyrow + l16) * 64 + ((quad + 4) ^ f8) * 8];
                float4 ma4 = *(const float4*)&sMaddAll[kt + keyrow + quad * 4];
#pragma unroll
                for (int qt = 0; qt < 4; qt++) {
                    f32x4 c = (f32x4){0.f, 0.f, 0.f, 0.f};
                    c = __builtin_amdgcn_mfma_f32_16x16x32_bf16(ak0, aq[qt][0], c, 0, 0, 0);
                    c = __builtin_amdgcn_mfma_f32_16x16x32_bf16(ak1, aq[qt][1], c, 0, 0, 0);
                    float p0 = __builtin_amdgcn_exp2f(c[0] + ma4.x);
                    float p1 = __builtin_amdgcn_exp2f(c[1] + ma4.y);
                    float p2 = __builtin_amdgcn_exp2f(c[2] + ma4.z);
                    float p3 = __builtin_amdgcn_exp2f(c[3] + ma4.w);
                    psum[qt] += (p0 + p1) + (p2 + p3);
                    bf16x4 pk = { f2bf(p0), f2bf(p1), f2bf(p2), f2bf(p3) };
                    *(bf16x4*)&sP[wave][(qt * 16 + l16) * 40 + (mtl * 4 + quad) * 4] = pk;
                }
            }

            // --- O += P @ V (A=P[q][k32], B=V^T[d][k32]) ---
            WAIT_LGKM0();   // same-wave sP write -> read drain (R2 rule)
            bf16x8 ap[4];
#pragma unroll
            for (int qt = 0; qt < 4; qt++)
                ap[qt] = *(const bf16x8*)&sP[wave][(qt * 16 + l16) * 40 + quad * 8];
#pragma unroll
            for (int dt = 0; dt < 4; dt++) {
                int g = (kh * 8 + pass * 4 + quad) ^ l16;    // sV group slot
                bf16x8 bv = *(const bf16x8*)&sV[(dt * 16 + l16) * 128 + g * 8];
#pragma unroll
                for (int qt = 0; qt < 4; qt++)
                    o[qt][dt] = __builtin_amdgcn_mfma_f32_16x16x32_bf16(ap[qt], bv, o[qt][dt], 0, 0, 0);
            }
        }
        __syncthreads();   // all fragment reads done before next staging
    }

    // reduce psum over quads (keys within the wave) -> full per-(q, key-half)
#pragma unroll
    for (int qt = 0; qt < 4; qt++) {
        float v = psum[qt];
        v += __shfl_xor(v, 16);
        v += __shfl_xor(v, 32);
        psum[qt] = v;
    }

    // cross-wave reduction: waves 2,3 (key-half 1) hand partials to waves 0,1.
    __syncthreads();
    float* sRed = (wave == 2) ? (float*)sK : (float*)sV;   // 16KB each
    if (wave >= 2) {
#pragma unroll
        for (int qt = 0; qt < 4; qt++)
#pragma unroll
            for (int dt = 0; dt < 4; dt++)
                *(f32x4*)&sRed[((qt * 4 + dt) * 64 + lane) * 4] = o[qt][dt];
#pragma unroll
        for (int qt = 0; qt < 4; qt++)
            sPsumR[(wave - 2) * 64 + qt * 16 + l16] = psum[qt];  // all quads same value
    }
    __syncthreads();
    if (wave < 2) {
        float* src = (wave == 0) ? (float*)sK : (float*)sV;
#pragma unroll
        for (int qt = 0; qt < 4; qt++)
#pragma unroll
            for (int dt = 0; dt < 4; dt++)
                o[qt][dt] += *(const f32x4*)&src[((qt * 4 + dt) * 64 + lane) * 4];
        // combined psum, then broadcast across quads via LDS (q index remap)
#pragma unroll
        for (int qt = 0; qt < 4; qt++) {
            float v = psum[qt] + sPsumR[wave * 64 + qt * 16 + l16];
            sPsumF[wave * 64 + qt * 16 + l16] = v;
        }
        WAIT_LGKM0();   // same-wave write -> read
        int h = bh & 15;
#pragma unroll
        for (int qt = 0; qt < 4; qt++) {
            float4 ps = *(const float4*)&sPsumF[wave * 64 + qt * 16 + quad * 4];
            float rcp[4] = { 1.f / ps.x, 1.f / ps.y, 1.f / ps.z, 1.f / ps.w };
#pragma unroll
            for (int r = 0; r < 4; r++) {
                int s = q0 + qh * 64 + qt * 16 + quad * 4 + r;
#pragma unroll
                for (int dt = 0; dt < 4; dt++) {
                    int d = dt * 16 + l16;
                    Og[((size_t)(b * S_ + s)) * D_ + h * 64 + d] = f2bf(o[qt][dt][r] * rcp[r]);
                }
            }
        }
    }
}

// ---------------------------------------------------------------------------
extern "C" void kernel_launch(void* const* d_in, const int* in_sizes, int n_in,
                              void* d_out, int out_size, void* d_ws, size_t ws_size,
                              hipStream_t stream) {
    const float* hs = (const float*)d_in[0];
    const int* mask = (const int*)d_in[1];
    const float* Wq = (const float*)d_in[2];
    const float* bq = (const float*)d_in[3];
    const float* Wk = (const float*)d_in[4];
    const float* bk = (const float*)d_in[5];
    const float* Wv = (const float*)d_in[6];
    const float* bv = (const float*)d_in[7];
    const float* Wo = (const float*)d_in[8];
    const float* bo = (const float*)d_in[9];
    float* out = (float*)d_out;

    char* ws = (char*)d_ws;
    bf16* hsb  = (bf16*)(ws);                          // 8 MB (4096x1024)
    bf16* wqkv = (bf16*)(ws + ((size_t)8 << 20));      // 6 MB (3072x1024)
    bf16* wob  = (bf16*)(ws + ((size_t)14 << 20));     // 2 MB (1024x1024)
    bf16* Qw   = (bf16*)(ws + ((size_t)16 << 20));     // 8 MB (b,h,s,d)
    bf16* Kw   = (bf16*)(ws + ((size_t)24 << 20));     // 8 MB (b,h,s,d)
    bf16* Vtw  = (bf16*)(ws + ((size_t)32 << 20));     // 8 MB (b,h,d,s)
    bf16* attn = (bf16*)(ws + ((size_t)40 << 20));     // 8 MB (b,s,h*64+d)

    cvt_kernel<<<8192, 256, 0, stream>>>(hs, Wq, Wk, Wv, Wo, hsb, wqkv, wob);
    gemm_bt<<<dim3(32, 24), 256, 0, stream>>>(hsb, wqkv, bq, bk, bv,
                                              Qw, Kw, Vtw);
    attn_kernel<<<dim3(16, 32), 256, 0, stream>>>(Qw, Kw, Vtw, mask, attn);
    gemm_out<<<dim3(32, 16), 256, 0, stream>>>(attn, wob, bo, out);
}